// Round 25
// baseline (331.196 us; speedup 1.0000x reference)
//
#include <hip/hip_runtime.h>

#define N_NODES 100000
#define EDGES   1600000
#define H 64
#define OFFPAD 100352
#define NB2 391         // 256-node buckets
#define CHUNK 8192
#define NCHUNK 196      // ceil(EDGES/CHUNK)
#define LOSTRIDE 392    // NB2+1
#define BCAP 5120
#define GP300 1563
#define GSORT 392
#define GP64  1563
#define GB 1563         // sage blocks per side
#define AGROUPS 392     // phaseA interleave groups (period 9)

typedef unsigned int u32;
typedef unsigned short u16;
typedef short bf16x8 __attribute__((ext_vector_type(8)));
typedef float f32x4  __attribute__((ext_vector_type(4)));

__device__ __forceinline__ void bfsplit(float x, u32& h, u32& lo) {
    union { float f; u32 u; } c; c.f = x;
    u32 hu = (c.u + 0x7fffu + ((c.u >> 16) & 1u)) & 0xffff0000u;
    h = hu >> 16;
    union { u32 u; float f; } hb; hb.u = hu;
    union { float f; u32 u; } r; r.f = x - hb.f;
    lo = (r.u + 0x7fffu + ((r.u >> 16) & 1u)) >> 16;
}
__device__ __forceinline__ u16 bfrne(float x) {
    union { float f; u32 u; } c; c.f = x;
    return (u16)((c.u + 0x7fffu + ((c.u >> 16) & 1u)) >> 16);
}
__device__ __forceinline__ float bflo(u32 w)  { union { u32 u; float f; } c; c.u = w << 16; return c.f; }
__device__ __forceinline__ float bfhi(u32 w)  { union { u32 u; float f; } c; c.u = w & 0xffff0000u; return c.f; }

// ---------- weight prep + fold_head + sz zero, one dispatch (81 blocks) ----------
__global__ __launch_bounds__(256) void prep_weights(
    const float* __restrict__ w_a, const float* __restrict__ w_u,
    const float* __restrict__ b_wl, const float* __restrict__ b_wr,
    const float* __restrict__ p_wl, const float* __restrict__ p_wr,
    u32* __restrict__ pa_h, u32* __restrict__ pa_l,
    u32* __restrict__ pu_h, u32* __restrict__ pu_l,
    u32* __restrict__ pb_h, u32* __restrict__ pb_l,
    u32* __restrict__ pp_h, u32* __restrict__ pp_l,
    const float* __restrict__ w_out, const float* __restrict__ wl2,
    const float* __restrict__ wr2, const float* __restrict__ bl2,
    const float* __restrict__ b_out, float* __restrict__ headW,
    int* __restrict__ sz_zero)
{
    if (blockIdx.x == 80) {
        const int t = threadIdx.x;
        for (int i = t; i < 1024; i += 256) sz_zero[i] = 0;
        if (t < 128) {
            int o = t >> 6, j = t & 63;
            float s = 0.f;
            for (int h = 0; h < 64; ++h) s += w_out[o * 64 + h] * wl2[h * 64 + j];
            headW[o * 64 + j] = s;
        } else {
            int idx = t - 128, o = idx >> 6, j = idx & 63;
            float s = 0.f;
            for (int h = 0; h < 64; ++h) s += w_out[o * 64 + h] * wr2[h * 64 + j];
            headW[128 + o * 64 + j] = s;
        }
        if (t < 2) {
            float s = b_out[t];
            for (int h = 0; h < 64; ++h) s += w_out[t * 64 + h] * bl2[h];
            headW[256 + t] = s;
        }
        return;
    }
    const int t = blockIdx.x * 256 + threadIdx.x;
    float v0 = 0.f, v1 = 0.f; u32* dh; u32* dl; int idx;
    if (t < 10240) {
        const int row = t / 160, u = t - row * 160, k = 2 * u;
        if (k < 300)     v0 = w_a[row * 300 + k];
        if (k + 1 < 300) v1 = w_a[row * 300 + k + 1];
        dh = pa_h; dl = pa_l; idx = t;
    } else if (t < 12288) {
        idx = t - 10240;
        const int row = idx >> 5, u = idx & 31, k = 2 * u;
        v0 = w_u[row * 64 + k]; v1 = w_u[row * 64 + k + 1];
        dh = pu_h; dl = pu_l;
    } else if (t < 16384) {
        idx = t - 12288;
        const int row = idx >> 6, u = idx & 63, k = 2 * u;
        if (k < 64) { v0 = b_wl[row * 64 + k];      v1 = b_wl[row * 64 + k + 1]; }
        else        { v0 = b_wr[row * 64 + k - 64]; v1 = b_wr[row * 64 + k - 63]; }
        dh = pb_h; dl = pb_l;
    } else {
        idx = t - 16384;
        const int row = idx >> 6, u = idx & 63, k = 2 * u;
        if (k < 64) { v0 = p_wl[row * 64 + k];      v1 = p_wl[row * 64 + k + 1]; }
        else        { v0 = p_wr[row * 64 + k - 64]; v1 = p_wr[row * 64 + k - 63]; }
        dh = pp_h; dl = pp_l;
    }
    u32 h0, l0, h1, l1; bfsplit(v0, h0, l0); bfsplit(v1, h1, l1);
    dh[idx] = h0 | (h1 << 16);
    dl[idx] = l0 | (l1 << 16);
}

// ---------- proj body: A-frags in registers; W prefetched to regs, written to LDS late ----------
template<int D, int KPAD>
__device__ __forceinline__ void proj_body(
    int blk, const float* __restrict__ x,
    const u32* __restrict__ wh_g, const u32* __restrict__ wl_g,
    const float* __restrict__ b, float* __restrict__ out, u16* __restrict__ outb,
    u32* smem)
{
    constexpr int NT = KPAD / 64;
    u32* Wh = smem;
    u32* Wl = smem + 2048;
    const int tid  = threadIdx.x;
    const int base = blk * 64;
    const int l  = tid & 63;
    const int wv = tid >> 6;
    const int arow = wv * 16 + (l & 15);
    const int rr   = min(base + arow, N_NODES - 1);
    const int kg = l >> 4;
    f32x4 acc[4] = {};

    float4 xreg[4];
    auto loadX = [&](int t) {
        const int k0 = t * 64;
        #pragma unroll
        for (int s = 0; s < 2; ++s) {
            #pragma unroll
            for (int h = 0; h < 2; ++h) {
                const int kk = k0 + s * 32 + kg * 8 + 4 * h;
                float4 v = make_float4(0.f, 0.f, 0.f, 0.f);
                if (kk + 4 <= D) {
                    v = *(const float4*)&x[(size_t)rr * D + kk];
                } else {
                    const float* xr = &x[(size_t)rr * D];
                    if (kk     < D) v.x = xr[kk];
                    if (kk + 1 < D) v.y = xr[kk + 1];
                    if (kk + 2 < D) v.z = xr[kk + 2];
                    if (kk + 3 < D) v.w = xr[kk + 3];
                }
                xreg[s * 2 + h] = v;
            }
        }
    };
    uint2 wreg_h[4], wreg_l[4];
    auto loadW = [&](int t) {
        #pragma unroll
        for (int it = 0; it < 4; ++it) {
            const int i = tid + it * 256;
            const int row = i >> 4, j = i & 15;
            const int u = 2 * j;
            const int wo = row * (KPAD / 2) + t * 32 + u;
            wreg_h[it] = *(const uint2*)&wh_g[wo];
            wreg_l[it] = *(const uint2*)&wl_g[wo];
        }
    };
    auto writeW = [&]() {
        #pragma unroll
        for (int it = 0; it < 4; ++it) {
            const int i = tid + it * 256;
            const int row = i >> 4, j = i & 15;
            const int u = 2 * j;
            const int widx = (row << 5) | (u ^ ((row & 7) << 2));
            *(uint2*)&Wh[widx] = wreg_h[it];
            *(uint2*)&Wl[widx] = wreg_l[it];
        }
    };

    union FragU { u32 w[4]; bf16x8 v; };
    FragU fh[2], fl[2];
    auto buildFrags = [&]() {
        #pragma unroll
        for (int s = 0; s < 2; ++s) {
            #pragma unroll
            for (int h = 0; h < 2; ++h) {
                const float4 v = xreg[s * 2 + h];
                u32 h0, l0, h1, l1, h2, l2, h3, l3;
                bfsplit(v.x, h0, l0); bfsplit(v.y, h1, l1);
                bfsplit(v.z, h2, l2); bfsplit(v.w, h3, l3);
                fh[s].w[h * 2 + 0] = h0 | (h1 << 16);
                fh[s].w[h * 2 + 1] = h2 | (h3 << 16);
                fl[s].w[h * 2 + 0] = l0 | (l1 << 16);
                fl[s].w[h * 2 + 1] = l2 | (l3 << 16);
            }
        }
    };

    loadX(0);
    loadW(0);
    writeW();
    __syncthreads();

    for (int t = 0; t < NT; ++t) {
        buildFrags();
        if (t + 1 < NT) { loadX(t + 1); loadW(t + 1); }
        #pragma unroll
        for (int s = 0; s < 2; ++s) {
            const bf16x8 ah = fh[s].v;
            const bf16x8 al = fl[s].v;
            #pragma unroll
            for (int c = 0; c < 4; ++c) {
                const int brow = c * 16 + (l & 15);
                const int kb = (brow << 5) | ((s * 16 + kg * 4) ^ ((brow & 7) << 2));
                const bf16x8 bh = *(const bf16x8*)&Wh[kb];
                const bf16x8 bl = *(const bf16x8*)&Wl[kb];
                acc[c] = __builtin_amdgcn_mfma_f32_16x16x32_bf16(ah, bh, acc[c], 0, 0, 0);
                acc[c] = __builtin_amdgcn_mfma_f32_16x16x32_bf16(ah, bl, acc[c], 0, 0, 0);
                acc[c] = __builtin_amdgcn_mfma_f32_16x16x32_bf16(al, bh, acc[c], 0, 0, 0);
            }
        }
        __syncthreads();
        if (t + 1 < NT) {
            writeW();
            __syncthreads();
        }
    }

    const int orow0 = base + wv * 16 + (l >> 4) * 4;
    #pragma unroll
    for (int c = 0; c < 4; ++c) {
        const int col = c * 16 + (l & 15);
        const float bv = b[col];
        #pragma unroll
        for (int i = 0; i < 4; ++i) {
            const int row = orow0 + i;
            if (row < N_NODES) {
                const float v = fmaxf(acc[c][i] + bv, 0.f);
                out[(size_t)row * H + col] = v;
                outb[(size_t)row * H + col] = bfrne(v);
            }
        }
    }
}

// ---------- sort body ----------
__device__ __forceinline__ void sort_body(
    int b, const int* __restrict__ ei,
    int* __restrict__ lo, int* __restrict__ sz, int* __restrict__ raw,
    u32* smem)
{
    int* cnt = (int*)smem;
    int* loc = (int*)smem + NB2;
    const int tid = threadIdx.x;
    const int e0 = b * CHUNK, e1 = min(e0 + CHUNK, EDGES);

    for (int i = tid; i < NB2; i += 256) cnt[i] = 0;
    __syncthreads();
    for (int e = e0 + tid; e < e1; e += 256)
        atomicAdd(&cnt[ei[EDGES + e] >> 8], 1);
    __syncthreads();
    for (int i = tid; i < NB2; i += 256)
        if (cnt[i]) atomicAdd(&sz[i], cnt[i]);
    if (tid == 0) {
        int run = 0;
        for (int i = 0; i < NB2; ++i) { loc[i] = run; run += cnt[i]; }
        loc[NB2] = run;
    }
    __syncthreads();
    for (int i = tid; i <= NB2; i += 256) lo[b * LOSTRIDE + i] = loc[i];
    for (int i = tid; i < NB2; i += 256) cnt[i] = loc[i];
    __syncthreads();
    for (int e = e0 + tid; e < e1; e += 256) {
        const int d = ei[EDGES + e], s = ei[e];
        const int pos = atomicAdd(&cnt[d >> 8], 1);
        raw[e0 + pos] = (s << 8) | (d & 255);
    }
}

// ---------- phase A: INTERLEAVED proj300 | sort | proj64 (period-9 pattern 4:1:4) ----------
__global__ __launch_bounds__(256) void phaseA(
    const float* __restrict__ x_a, const u32* __restrict__ pa_h, const u32* __restrict__ pa_l,
    const float* __restrict__ b_in_a, float* __restrict__ bufA, u16* __restrict__ fAb,
    const float* __restrict__ x_u, const u32* __restrict__ pu_h, const u32* __restrict__ pu_l,
    const float* __restrict__ b_in_u, float* __restrict__ bufU, u16* __restrict__ fUb,
    const int* __restrict__ ei_p, const int* __restrict__ ei_b,
    int* __restrict__ lo_p, int* __restrict__ lo_b,
    int* __restrict__ sz_p, int* __restrict__ sz_b,
    int* __restrict__ raw_p, int* __restrict__ raw_b)
{
    __shared__ u32 smem[4096];
    const int g = blockIdx.x / 9;
    const int r = blockIdx.x % 9;
    if (r < 4) {
        const int id = g * 4 + r;
        if (id < GP300)
            proj_body<300, 320>(id, x_a, pa_h, pa_l, b_in_a, bufA, fAb, smem);
    } else if (r == 4) {
        const int id = g;
        if (id < GSORT) {
            if (id < NCHUNK) sort_body(id, ei_p, lo_p, sz_p, raw_p, smem);
            else             sort_body(id - NCHUNK, ei_b, lo_b, sz_b, raw_b, smem);
        }
    } else {
        const int id = g * 4 + (r - 5);
        if (id < GP64)
            proj_body<64, 64>(id, x_u, pu_h, pu_l, b_in_u, bufU, fUb, smem);
    }
}

// ---------- tiny scan of bucket sizes ----------
__global__ __launch_bounds__(256) void scan_boff(
    const int* __restrict__ sz_p, const int* __restrict__ sz_b,
    int* __restrict__ boff_p, int* __restrict__ boff_b,
    int* __restrict__ off_p, int* __restrict__ off_b)
{
    __shared__ int part[256];
    const int* sz = blockIdx.x ? sz_b : sz_p;
    int* boff = blockIdx.x ? boff_b : boff_p;
    int* off  = blockIdx.x ? off_b : off_p;
    const int t = threadIdx.x;
    const int i0 = 2 * t, i1 = 2 * t + 1;
    const int v0 = (i0 < NB2) ? sz[i0] : 0;
    const int v1 = (i1 < NB2) ? sz[i1] : 0;
    part[t] = v0 + v1;
    __syncthreads();
    for (int d = 1; d < 256; d <<= 1) {
        int x = (t >= d) ? part[t - d] : 0;
        __syncthreads();
        part[t] += x;
        __syncthreads();
    }
    const int excl = part[t] - (v0 + v1);
    if (i0 < NB2) boff[i0] = excl;
    if (i1 < NB2) boff[i1] = excl + v0;
    if (t == 0) { boff[NB2] = EDGES; off[N_NODES] = EDGES; }
}

// ---------- level 2 sort: LDS-staged scatter, coalesced csr write ----------
__global__ __launch_bounds__(256) void bucket_sort2(
    const int* __restrict__ raw_p, const int* __restrict__ raw_b,
    const int* __restrict__ lo_p, const int* __restrict__ lo_b,
    const int* __restrict__ boff_p, const int* __restrict__ boff_b,
    int* __restrict__ off_p, int* __restrict__ off_b,
    int* __restrict__ csr_p, int* __restrict__ csr_b)
{
    __shared__ int cnt[256];
    __shared__ int cur[256];
    __shared__ int sb[NCHUNK], se[NCHUNK];
    __shared__ int stage[BCAP];
    int k = blockIdx.x;
    const int* raw; const int* lo; const int* boff; int* off; int* csr;
    if (k < NB2) { raw = raw_p; lo = lo_p; boff = boff_p; off = off_p; csr = csr_p; }
    else { k -= NB2; raw = raw_b; lo = lo_b; boff = boff_b; off = off_b; csr = csr_b; }
    const int tid = threadIdx.x;
    cnt[tid] = 0;
    if (tid < NCHUNK) {
        sb[tid] = lo[tid * LOSTRIDE + k];
        se[tid] = lo[tid * LOSTRIDE + k + 1];
    }
    __syncthreads();
    if (tid < NCHUNK) {
        const int base = tid * CHUNK;
        for (int e = sb[tid]; e < se[tid]; ++e)
            atomicAdd(&cnt[raw[base + e] & 255], 1);
    }
    __syncthreads();
    if (tid == 0) {
        int run = 0;
        for (int i = 0; i < 256; ++i) { cur[i] = run; run += cnt[i]; }
    }
    __syncthreads();
    const int bbeg = boff[k];
    const int bsz  = boff[k + 1] - bbeg;
    {
        const int node = (k << 8) + tid;
        if (node < N_NODES) off[node] = bbeg + cur[tid];
    }
    __syncthreads();
    if (bsz <= BCAP) {
        if (tid < NCHUNK) {
            const int base = tid * CHUNK;
            for (int e = sb[tid]; e < se[tid]; ++e) {
                const int id = raw[base + e];
                const int pos = atomicAdd(&cur[id & 255], 1);
                stage[pos] = id >> 8;
            }
        }
        __syncthreads();
        for (int i = tid; i < bsz; i += 256)
            csr[bbeg + i] = stage[i];
    } else {
        if (tid < NCHUNK) {
            const int base = tid * CHUNK;
            for (int e = sb[tid]; e < se[tid]; ++e) {
                const int id = raw[base + e];
                const int pos = atomicAdd(&cur[id & 255], 1);
                csr[bbeg + pos] = id >> 8;
            }
        }
    }
}

// ---------- phase B: both gathers ----------
__global__ __launch_bounds__(256) void phaseB(
    int bstart,
    const u16* __restrict__ fAb, const int* __restrict__ off_b, const int* __restrict__ csr_b,
    float* __restrict__ agg1,
    const u16* __restrict__ fUb, const int* __restrict__ off_p, const int* __restrict__ csr_p,
    float* __restrict__ agg2)
{
    int node = (((blockIdx.x + bstart) * 256 + threadIdx.x) >> 6);
    const u16* featb; const int* off; const int* csr; float* agg;
    if (node < N_NODES) { featb = fAb; off = off_b; csr = csr_b; agg = agg1; }
    else { node -= N_NODES; featb = fUb; off = off_p; csr = csr_p; agg = agg2; }
    const int lane = threadIdx.x & 63;
    const int grp  = lane >> 3;
    const int q    = lane & 7;
    const u32* fb = (const u32*)featb;
    const int beg = off[node], end = off[node + 1];
    float a0=0.f,a1=0.f,a2=0.f,a3=0.f,a4=0.f,a5=0.f,a6=0.f,a7=0.f;
    for (int e = beg + grp; e < end; e += 8) {
        const int s = csr[e];
        const uint4 v = *(const uint4*)&fb[((size_t)s << 5) + (q << 2)];
        a0 += bflo(v.x); a1 += bfhi(v.x);
        a2 += bflo(v.y); a3 += bfhi(v.y);
        a4 += bflo(v.z); a5 += bfhi(v.z);
        a6 += bflo(v.w); a7 += bfhi(v.w);
    }
    #pragma unroll
    for (int m = 8; m <= 32; m <<= 1) {
        a0 += __shfl_xor(a0, m, 64); a1 += __shfl_xor(a1, m, 64);
        a2 += __shfl_xor(a2, m, 64); a3 += __shfl_xor(a3, m, 64);
        a4 += __shfl_xor(a4, m, 64); a5 += __shfl_xor(a5, m, 64);
        a6 += __shfl_xor(a6, m, 64); a7 += __shfl_xor(a7, m, 64);
    }
    if (grp == 0) {
        const float inv = 1.0f / fmaxf((float)(end - beg), 1.0f);
        float4 o0 = make_float4(a0 * inv, a1 * inv, a2 * inv, a3 * inv);
        float4 o1 = make_float4(a4 * inv, a5 * inv, a6 * inv, a7 * inv);
        *(float4*)&agg[(size_t)node * H + 8 * q]     = o0;
        *(float4*)&agg[(size_t)node * H + 8 * q + 4] = o1;
    }
}

// ---------- phase C: both SAGE updates ----------
__global__ __launch_bounds__(256) void phaseC(
    int bstart,
    const float* __restrict__ agg1, const float* __restrict__ xu,
    const u32* __restrict__ pb_h, const u32* __restrict__ pb_l, const float* __restrict__ bl_b,
    const float* __restrict__ agg2, const float* __restrict__ xa,
    const u32* __restrict__ pp_h, const u32* __restrict__ pp_l, const float* __restrict__ bl_p,
    const float* __restrict__ headW, float* __restrict__ z, float* __restrict__ outA)
{
    __shared__ u32 Ah[4096], Al[4096];
    union ShW { u32 w[4096]; float us[64 * 65]; };
    __shared__ ShW shw;
    int blk = blockIdx.x + bstart;
    const bool zhead = (blk < GB);
    const float* A1; const float* A2; const u32* wh_g; const u32* wl_g; const float* bias;
    if (zhead) { A1 = agg1; A2 = xu; wh_g = pb_h; wl_g = pb_l; bias = bl_b; }
    else { blk -= GB; A1 = agg2; A2 = xa; wh_g = pp_h; wl_g = pp_l; bias = bl_p; }
    const int tid  = threadIdx.x;
    const int base = blk * 64;
    const int l  = tid & 63;
    const int wv = tid >> 6;
    const int arow = wv * 16 + (l & 15);
    const int kg = l >> 4;
    f32x4 acc[4] = {};

    for (int i = tid; i < 4096; i += 256) {
        const int row = i >> 6, u = i & 63;
        const int k = 2 * u;
        const int rr = min(base + row, N_NODES - 1);
        const float2 v = (k < 64)
            ? *(const float2*)&A1[(size_t)rr * H + k]
            : *(const float2*)&A2[(size_t)rr * H + (k - 64)];
        u32 h0, l0, h1, l1;
        bfsplit(v.x, h0, l0); bfsplit(v.y, h1, l1);
        const int widx = (row << 6) | (u ^ ((row & 7) << 2));
        Ah[widx] = h0 | (h1 << 16);
        Al[widx] = l0 | (l1 << 16);
    }

    #pragma unroll
    for (int t = 0; t < 2; ++t) {
        for (int i = tid; i < 2048; i += 256) {
            const int row = i >> 5, u = i & 31;
            const int widx = (row << 5) | (u ^ ((row & 7) << 2));
            shw.w[widx]        = wh_g[row * 64 + t * 32 + u];
            shw.w[2048 + widx] = wl_g[row * 64 + t * 32 + u];
        }
        __syncthreads();
        #pragma unroll
        for (int s = 0; s < 2; ++s) {
            const int ka = (arow << 6) + ((t * 32 + s * 16 + kg * 4) ^ ((arow & 7) << 2));
            const bf16x8 ah = *(const bf16x8*)&Ah[ka];
            const bf16x8 al = *(const bf16x8*)&Al[ka];
            #pragma unroll
            for (int c = 0; c < 4; ++c) {
                const int brow = c * 16 + (l & 15);
                const int kb = (brow << 5) + ((s * 16 + kg * 4) ^ ((brow & 7) << 2));
                const bf16x8 bh = *(const bf16x8*)&shw.w[kb];
                const bf16x8 bl = *(const bf16x8*)&shw.w[2048 + kb];
                acc[c] = __builtin_amdgcn_mfma_f32_16x16x32_bf16(ah, bh, acc[c], 0, 0, 0);
                acc[c] = __builtin_amdgcn_mfma_f32_16x16x32_bf16(ah, bl, acc[c], 0, 0, 0);
                acc[c] = __builtin_amdgcn_mfma_f32_16x16x32_bf16(al, bh, acc[c], 0, 0, 0);
            }
        }
        __syncthreads();
    }

    const int r0 = wv * 16 + (l >> 4) * 4;
    if (!zhead) {
        #pragma unroll
        for (int c = 0; c < 4; ++c) {
            const int col = c * 16 + (l & 15);
            const float bv = bias[col];
            #pragma unroll
            for (int i = 0; i < 4; ++i) {
                const int row = base + r0 + i;
                if (row < N_NODES)
                    outA[(size_t)row * H + col] = fmaxf(acc[c][i] + bv, 0.f);
            }
        }
    } else {
        #pragma unroll
        for (int c = 0; c < 4; ++c) {
            const int col = c * 16 + (l & 15);
            const float bv = bias[col];
            #pragma unroll
            for (int i = 0; i < 4; ++i)
                shw.us[(r0 + i) * 65 + col] = fmaxf(acc[c][i] + bv, 0.f);
        }
        __syncthreads();
        if (tid < 128) {
            const int r = tid & 63, o = tid >> 6;
            const int row = base + r;
            if (row < N_NODES) {
                float v = 0.f;
                for (int k = 0; k < 64; ++k)
                    v += shw.us[r * 65 + k] * headW[o * 64 + k];
                z[(size_t)row * 2 + o] = v;
            }
        }
    }
}

// ---------- final head ----------
__global__ __launch_bounds__(256) void final_head(
    const int* __restrict__ off, const int* __restrict__ csr,
    const float* __restrict__ z, const float* __restrict__ a1,
    const float* __restrict__ headW, float* __restrict__ out)
{
    const int node = (blockIdx.x * 256 + threadIdx.x) >> 6;
    const int lane = threadIdx.x & 63;
    const int beg = off[node], end = off[node + 1];
    float z0 = 0.f, z1 = 0.f;
    for (int e = beg + lane; e < end; e += 64) {
        int s = csr[e];
        const float2 zv = *(const float2*)&z[(size_t)s * 2];
        z0 += zv.x; z1 += zv.y;
    }
    const float av = a1[(size_t)node * H + lane];
    float p0 = av * headW[128 + lane];
    float p1 = av * headW[192 + lane];
    #pragma unroll
    for (int m = 1; m <= 32; m <<= 1) {
        z0 += __shfl_xor(z0, m, 64);
        z1 += __shfl_xor(z1, m, 64);
        p0 += __shfl_xor(p0, m, 64);
        p1 += __shfl_xor(p1, m, 64);
    }
    if (lane == 0) {
        const float inv = 1.0f / fmaxf((float)(end - beg), 1.0f);
        float2 o;
        o.x = z0 * inv + p0 + headW[256];
        o.y = z1 * inv + p1 + headW[257];
        *(float2*)&out[(size_t)node * 2] = o;
    }
}

extern "C" void kernel_launch(void* const* d_in, const int* in_sizes, int n_in,
                              void* d_out, int out_size, void* d_ws, size_t ws_size,
                              hipStream_t stream) {
    const float* x_a    = (const float*)d_in[0];
    const float* x_u    = (const float*)d_in[1];
    const int*   ei_p   = (const int*)d_in[2];
    const int*   ei_b   = (const int*)d_in[3];
    const float* w_in_a = (const float*)d_in[4];
    const float* b_in_a = (const float*)d_in[5];
    const float* w_in_u = (const float*)d_in[6];
    const float* b_in_u = (const float*)d_in[7];
    const float* c1p_wl = (const float*)d_in[8];
    const float* c1p_bl = (const float*)d_in[9];
    const float* c1p_wr = (const float*)d_in[10];
    const float* c1b_wl = (const float*)d_in[11];
    const float* c1b_bl = (const float*)d_in[12];
    const float* c1b_wr = (const float*)d_in[13];
    const float* c2p_wl = (const float*)d_in[14];
    const float* c2p_bl = (const float*)d_in[15];
    const float* c2p_wr = (const float*)d_in[16];
    const float* w_out  = (const float*)d_in[20];
    const float* b_out  = (const float*)d_in[21];

    const size_t NF = (size_t)N_NODES * H;
    const size_t PAR_NEED =
        (4 * NF + NF + 2 * N_NODES + 512) * 4 +
        ((size_t)2 * 77056 + 4 * 512 + 2 * OFFPAD + 2 * EDGES) * 4 +
        (size_t)40960 * 4;
    const bool par = ws_size >= PAR_NEED;

    float* bufA  = (float*)d_ws;
    float* bufU  = bufA + NF;
    float* agg1  = bufU + NF;
    float* agg2  = par ? (agg1 + NF) : agg1;
    float* nxt   = par ? (agg2 + NF) : (agg1 + NF);
    u16*   fAb   = (u16*)nxt;
    u16*   fUb   = fAb + NF;
    float* z     = (float*)(fUb + NF);
    float* headW = z + 2 * N_NODES;
    int* lo_p   = (int*)(headW + 512);
    int* lo_b   = lo_p + 77056;
    int* sz_p   = lo_b + 77056;
    int* sz_b   = sz_p + 512;
    int* boff_p = sz_b + 512;
    int* boff_b = boff_p + 512;
    int* off_p  = boff_b + 512;
    int* off_b  = off_p + OFFPAD;
    int* csr_p  = off_b + OFFPAD;
    int* csr_b  = csr_p + EDGES;
    u32* pa_h   = (u32*)(csr_b + EDGES);
    u32* pa_l   = pa_h + 10240;
    u32* pu_h   = pa_l + 10240;
    u32* pu_l   = pu_h + 2048;
    u32* pb_h   = pu_l + 2048;
    u32* pb_l   = pb_h + 4096;
    u32* pp_h   = pb_l + 4096;
    u32* pp_l   = pp_h + 4096;
    int* raw_p  = (int*)agg1;
    int* raw_b  = raw_p + EDGES;

    const dim3 blk(256);

    prep_weights<<<81, blk, 0, stream>>>(
        w_in_a, w_in_u, c1b_wl, c1b_wr, c1p_wl, c1p_wr,
        pa_h, pa_l, pu_h, pu_l, pb_h, pb_l, pp_h, pp_l,
        w_out, c2p_wl, c2p_wr, c2p_bl, b_out, headW, sz_p);

    phaseA<<<9 * AGROUPS, blk, 0, stream>>>(
        x_a, pa_h, pa_l, b_in_a, bufA, fAb,
        x_u, pu_h, pu_l, b_in_u, bufU, fUb,
        ei_p, ei_b, lo_p, lo_b, sz_p, sz_b, raw_p, raw_b);

    scan_boff<<<2, blk, 0, stream>>>(sz_p, sz_b, boff_p, boff_b, off_p, off_b);
    bucket_sort2<<<2 * NB2, blk, 0, stream>>>(
        raw_p, raw_b, lo_p, lo_b, boff_p, boff_b, off_p, off_b, csr_p, csr_b);

    if (par) {
        phaseB<<<50000, blk, 0, stream>>>(0, fAb, off_b, csr_b, agg1, fUb, off_p, csr_p, agg2);
        phaseC<<<2 * GB, blk, 0, stream>>>(0,
            agg1, bufU, pb_h, pb_l, c1b_bl,
            agg2, bufA, pp_h, pp_l, c1p_bl, headW, z, bufA);
    } else {
        phaseB<<<25000, blk, 0, stream>>>(0, fAb, off_b, csr_b, agg1, fUb, off_p, csr_p, agg2);
        phaseC<<<GB, blk, 0, stream>>>(0,
            agg1, bufU, pb_h, pb_l, c1b_bl,
            agg2, bufA, pp_h, pp_l, c1p_bl, headW, z, bufA);
        phaseB<<<25000, blk, 0, stream>>>(25000, fAb, off_b, csr_b, agg1, fUb, off_p, csr_p, agg2);
        phaseC<<<GB, blk, 0, stream>>>(GB,
            agg1, bufU, pb_h, pb_l, c1b_bl,
            agg2, bufA, pp_h, pp_l, c1p_bl, headW, z, bufA);
    }

    final_head<<<25000, blk, 0, stream>>>(off_p, csr_p, z, bufA, headW, (float*)d_out);

    (void)in_sizes; (void)n_in; (void)out_size;
}

// Round 26
// 321.843 us; speedup vs baseline: 1.0291x; 1.0291x over previous
//
#include <hip/hip_runtime.h>

#define N_NODES 100000
#define EDGES   1600000
#define H 64
#define OFFPAD 100352
#define NB2 391         // 256-node buckets
#define CHUNK 8192
#define NCHUNK 196      // ceil(EDGES/CHUNK)
#define LOSTRIDE 392    // NB2+1
#define BCAP 5120
#define GP300 1563
#define GSORT 392
#define GP64  1563
#define GB 1563         // sage blocks per side

typedef unsigned int u32;
typedef unsigned short u16;
typedef short bf16x8 __attribute__((ext_vector_type(8)));
typedef float f32x4  __attribute__((ext_vector_type(4)));

__device__ __forceinline__ void bfsplit(float x, u32& h, u32& lo) {
    union { float f; u32 u; } c; c.f = x;
    u32 hu = (c.u + 0x7fffu + ((c.u >> 16) & 1u)) & 0xffff0000u;
    h = hu >> 16;
    union { u32 u; float f; } hb; hb.u = hu;
    union { float f; u32 u; } r; r.f = x - hb.f;
    lo = (r.u + 0x7fffu + ((r.u >> 16) & 1u)) >> 16;
}
__device__ __forceinline__ u16 bfrne(float x) {
    union { float f; u32 u; } c; c.f = x;
    return (u16)((c.u + 0x7fffu + ((c.u >> 16) & 1u)) >> 16);
}
__device__ __forceinline__ float bflo(u32 w)  { union { u32 u; float f; } c; c.u = w << 16; return c.f; }
__device__ __forceinline__ float bfhi(u32 w)  { union { u32 u; float f; } c; c.u = w & 0xffff0000u; return c.f; }

// ---------- weight prep + fold_head + sz zero, one dispatch (81 blocks) ----------
__global__ __launch_bounds__(256) void prep_weights(
    const float* __restrict__ w_a, const float* __restrict__ w_u,
    const float* __restrict__ b_wl, const float* __restrict__ b_wr,
    const float* __restrict__ p_wl, const float* __restrict__ p_wr,
    u32* __restrict__ pa_h, u32* __restrict__ pa_l,
    u32* __restrict__ pu_h, u32* __restrict__ pu_l,
    u32* __restrict__ pb_h, u32* __restrict__ pb_l,
    u32* __restrict__ pp_h, u32* __restrict__ pp_l,
    const float* __restrict__ w_out, const float* __restrict__ wl2,
    const float* __restrict__ wr2, const float* __restrict__ bl2,
    const float* __restrict__ b_out, float* __restrict__ headW,
    int* __restrict__ sz_zero)
{
    if (blockIdx.x == 80) {
        const int t = threadIdx.x;
        for (int i = t; i < 1024; i += 256) sz_zero[i] = 0;
        if (t < 128) {
            int o = t >> 6, j = t & 63;
            float s = 0.f;
            for (int h = 0; h < 64; ++h) s += w_out[o * 64 + h] * wl2[h * 64 + j];
            headW[o * 64 + j] = s;
        } else {
            int idx = t - 128, o = idx >> 6, j = idx & 63;
            float s = 0.f;
            for (int h = 0; h < 64; ++h) s += w_out[o * 64 + h] * wr2[h * 64 + j];
            headW[128 + o * 64 + j] = s;
        }
        if (t < 2) {
            float s = b_out[t];
            for (int h = 0; h < 64; ++h) s += w_out[t * 64 + h] * bl2[h];
            headW[256 + t] = s;
        }
        return;
    }
    const int t = blockIdx.x * 256 + threadIdx.x;
    float v0 = 0.f, v1 = 0.f; u32* dh; u32* dl; int idx;
    if (t < 10240) {
        const int row = t / 160, u = t - row * 160, k = 2 * u;
        if (k < 300)     v0 = w_a[row * 300 + k];
        if (k + 1 < 300) v1 = w_a[row * 300 + k + 1];
        dh = pa_h; dl = pa_l; idx = t;
    } else if (t < 12288) {
        idx = t - 10240;
        const int row = idx >> 5, u = idx & 31, k = 2 * u;
        v0 = w_u[row * 64 + k]; v1 = w_u[row * 64 + k + 1];
        dh = pu_h; dl = pu_l;
    } else if (t < 16384) {
        idx = t - 12288;
        const int row = idx >> 6, u = idx & 63, k = 2 * u;
        if (k < 64) { v0 = b_wl[row * 64 + k];      v1 = b_wl[row * 64 + k + 1]; }
        else        { v0 = b_wr[row * 64 + k - 64]; v1 = b_wr[row * 64 + k - 63]; }
        dh = pb_h; dl = pb_l;
    } else {
        idx = t - 16384;
        const int row = idx >> 6, u = idx & 63, k = 2 * u;
        if (k < 64) { v0 = p_wl[row * 64 + k];      v1 = p_wl[row * 64 + k + 1]; }
        else        { v0 = p_wr[row * 64 + k - 64]; v1 = p_wr[row * 64 + k - 63]; }
        dh = pp_h; dl = pp_l;
    }
    u32 h0, l0, h1, l1; bfsplit(v0, h0, l0); bfsplit(v1, h1, l1);
    dh[idx] = h0 | (h1 << 16);
    dl[idx] = l0 | (l1 << 16);
}

// ---------- proj body: A-frags in registers; W prefetched to regs, written to LDS late ----------
template<int D, int KPAD>
__device__ __forceinline__ void proj_body(
    int blk, const float* __restrict__ x,
    const u32* __restrict__ wh_g, const u32* __restrict__ wl_g,
    const float* __restrict__ b, float* __restrict__ out, u16* __restrict__ outb,
    u32* smem)
{
    constexpr int NT = KPAD / 64;
    u32* Wh = smem;
    u32* Wl = smem + 2048;
    const int tid  = threadIdx.x;
    const int base = blk * 64;
    const int l  = tid & 63;
    const int wv = tid >> 6;
    const int arow = wv * 16 + (l & 15);
    const int rr   = min(base + arow, N_NODES - 1);
    const int kg = l >> 4;
    f32x4 acc[4] = {};

    float4 xreg[4];
    auto loadX = [&](int t) {
        const int k0 = t * 64;
        #pragma unroll
        for (int s = 0; s < 2; ++s) {
            #pragma unroll
            for (int h = 0; h < 2; ++h) {
                const int kk = k0 + s * 32 + kg * 8 + 4 * h;
                float4 v = make_float4(0.f, 0.f, 0.f, 0.f);
                if (kk + 4 <= D) {
                    v = *(const float4*)&x[(size_t)rr * D + kk];
                } else {
                    const float* xr = &x[(size_t)rr * D];
                    if (kk     < D) v.x = xr[kk];
                    if (kk + 1 < D) v.y = xr[kk + 1];
                    if (kk + 2 < D) v.z = xr[kk + 2];
                    if (kk + 3 < D) v.w = xr[kk + 3];
                }
                xreg[s * 2 + h] = v;
            }
        }
    };
    uint2 wreg_h[4], wreg_l[4];
    auto loadW = [&](int t) {
        #pragma unroll
        for (int it = 0; it < 4; ++it) {
            const int i = tid + it * 256;
            const int row = i >> 4, j = i & 15;
            const int u = 2 * j;
            const int wo = row * (KPAD / 2) + t * 32 + u;
            wreg_h[it] = *(const uint2*)&wh_g[wo];
            wreg_l[it] = *(const uint2*)&wl_g[wo];
        }
    };
    auto writeW = [&]() {
        #pragma unroll
        for (int it = 0; it < 4; ++it) {
            const int i = tid + it * 256;
            const int row = i >> 4, j = i & 15;
            const int u = 2 * j;
            const int widx = (row << 5) | (u ^ ((row & 7) << 2));
            *(uint2*)&Wh[widx] = wreg_h[it];
            *(uint2*)&Wl[widx] = wreg_l[it];
        }
    };

    union FragU { u32 w[4]; bf16x8 v; };
    FragU fh[2], fl[2];
    auto buildFrags = [&]() {
        #pragma unroll
        for (int s = 0; s < 2; ++s) {
            #pragma unroll
            for (int h = 0; h < 2; ++h) {
                const float4 v = xreg[s * 2 + h];
                u32 h0, l0, h1, l1, h2, l2, h3, l3;
                bfsplit(v.x, h0, l0); bfsplit(v.y, h1, l1);
                bfsplit(v.z, h2, l2); bfsplit(v.w, h3, l3);
                fh[s].w[h * 2 + 0] = h0 | (h1 << 16);
                fh[s].w[h * 2 + 1] = h2 | (h3 << 16);
                fl[s].w[h * 2 + 0] = l0 | (l1 << 16);
                fl[s].w[h * 2 + 1] = l2 | (l3 << 16);
            }
        }
    };

    loadX(0);
    loadW(0);
    writeW();
    __syncthreads();

    for (int t = 0; t < NT; ++t) {
        buildFrags();
        if (t + 1 < NT) { loadX(t + 1); loadW(t + 1); }
        #pragma unroll
        for (int s = 0; s < 2; ++s) {
            const bf16x8 ah = fh[s].v;
            const bf16x8 al = fl[s].v;
            #pragma unroll
            for (int c = 0; c < 4; ++c) {
                const int brow = c * 16 + (l & 15);
                const int kb = (brow << 5) | ((s * 16 + kg * 4) ^ ((brow & 7) << 2));
                const bf16x8 bh = *(const bf16x8*)&Wh[kb];
                const bf16x8 bl = *(const bf16x8*)&Wl[kb];
                acc[c] = __builtin_amdgcn_mfma_f32_16x16x32_bf16(ah, bh, acc[c], 0, 0, 0);
                acc[c] = __builtin_amdgcn_mfma_f32_16x16x32_bf16(ah, bl, acc[c], 0, 0, 0);
                acc[c] = __builtin_amdgcn_mfma_f32_16x16x32_bf16(al, bh, acc[c], 0, 0, 0);
            }
        }
        __syncthreads();
        if (t + 1 < NT) {
            writeW();
            __syncthreads();
        }
    }

    const int orow0 = base + wv * 16 + (l >> 4) * 4;
    #pragma unroll
    for (int c = 0; c < 4; ++c) {
        const int col = c * 16 + (l & 15);
        const float bv = b[col];
        #pragma unroll
        for (int i = 0; i < 4; ++i) {
            const int row = orow0 + i;
            if (row < N_NODES) {
                const float v = fmaxf(acc[c][i] + bv, 0.f);
                out[(size_t)row * H + col] = v;
                outb[(size_t)row * H + col] = bfrne(v);
            }
        }
    }
}

// ---------- sort body ----------
__device__ __forceinline__ void sort_body(
    int b, const int* __restrict__ ei,
    int* __restrict__ lo, int* __restrict__ sz, int* __restrict__ raw,
    u32* smem)
{
    int* cnt = (int*)smem;
    int* loc = (int*)smem + NB2;
    const int tid = threadIdx.x;
    const int e0 = b * CHUNK, e1 = min(e0 + CHUNK, EDGES);

    for (int i = tid; i < NB2; i += 256) cnt[i] = 0;
    __syncthreads();
    for (int e = e0 + tid; e < e1; e += 256)
        atomicAdd(&cnt[ei[EDGES + e] >> 8], 1);
    __syncthreads();
    for (int i = tid; i < NB2; i += 256)
        if (cnt[i]) atomicAdd(&sz[i], cnt[i]);
    if (tid == 0) {
        int run = 0;
        for (int i = 0; i < NB2; ++i) { loc[i] = run; run += cnt[i]; }
        loc[NB2] = run;
    }
    __syncthreads();
    for (int i = tid; i <= NB2; i += 256) lo[b * LOSTRIDE + i] = loc[i];
    for (int i = tid; i < NB2; i += 256) cnt[i] = loc[i];
    __syncthreads();
    for (int e = e0 + tid; e < e1; e += 256) {
        const int d = ei[EDGES + e], s = ei[e];
        const int pos = atomicAdd(&cnt[d >> 8], 1);
        raw[e0 + pos] = (s << 8) | (d & 255);
    }
}

// ---------- phase A: proj300 | sort_fill(x2) | proj64 (sequential mapping, r24 best) ----------
__global__ __launch_bounds__(256) void phaseA(
    const float* __restrict__ x_a, const u32* __restrict__ pa_h, const u32* __restrict__ pa_l,
    const float* __restrict__ b_in_a, float* __restrict__ bufA, u16* __restrict__ fAb,
    const float* __restrict__ x_u, const u32* __restrict__ pu_h, const u32* __restrict__ pu_l,
    const float* __restrict__ b_in_u, float* __restrict__ bufU, u16* __restrict__ fUb,
    const int* __restrict__ ei_p, const int* __restrict__ ei_b,
    int* __restrict__ lo_p, int* __restrict__ lo_b,
    int* __restrict__ sz_p, int* __restrict__ sz_b,
    int* __restrict__ raw_p, int* __restrict__ raw_b)
{
    __shared__ u32 smem[4096];
    int blk = blockIdx.x;
    if (blk < GP300) {
        proj_body<300, 320>(blk, x_a, pa_h, pa_l, b_in_a, bufA, fAb, smem);
    } else if (blk < GP300 + GSORT) {
        int b = blk - GP300;
        if (b < NCHUNK) sort_body(b, ei_p, lo_p, sz_p, raw_p, smem);
        else            sort_body(b - NCHUNK, ei_b, lo_b, sz_b, raw_b, smem);
    } else {
        proj_body<64, 64>(blk - GP300 - GSORT, x_u, pu_h, pu_l, b_in_u, bufU, fUb, smem);
    }
}

// ---------- tiny scan of bucket sizes ----------
__global__ __launch_bounds__(256) void scan_boff(
    const int* __restrict__ sz_p, const int* __restrict__ sz_b,
    int* __restrict__ boff_p, int* __restrict__ boff_b,
    int* __restrict__ off_p, int* __restrict__ off_b)
{
    __shared__ int part[256];
    const int* sz = blockIdx.x ? sz_b : sz_p;
    int* boff = blockIdx.x ? boff_b : boff_p;
    int* off  = blockIdx.x ? off_b : off_p;
    const int t = threadIdx.x;
    const int i0 = 2 * t, i1 = 2 * t + 1;
    const int v0 = (i0 < NB2) ? sz[i0] : 0;
    const int v1 = (i1 < NB2) ? sz[i1] : 0;
    part[t] = v0 + v1;
    __syncthreads();
    for (int d = 1; d < 256; d <<= 1) {
        int x = (t >= d) ? part[t - d] : 0;
        __syncthreads();
        part[t] += x;
        __syncthreads();
    }
    const int excl = part[t] - (v0 + v1);
    if (i0 < NB2) boff[i0] = excl;
    if (i1 < NB2) boff[i1] = excl + v0;
    if (t == 0) { boff[NB2] = EDGES; off[N_NODES] = EDGES; }
}

// ---------- level 2 sort: LDS-staged scatter, coalesced csr write ----------
__global__ __launch_bounds__(256) void bucket_sort2(
    const int* __restrict__ raw_p, const int* __restrict__ raw_b,
    const int* __restrict__ lo_p, const int* __restrict__ lo_b,
    const int* __restrict__ boff_p, const int* __restrict__ boff_b,
    int* __restrict__ off_p, int* __restrict__ off_b,
    int* __restrict__ csr_p, int* __restrict__ csr_b)
{
    __shared__ int cnt[256];
    __shared__ int cur[256];
    __shared__ int sb[NCHUNK], se[NCHUNK];
    __shared__ int stage[BCAP];
    int k = blockIdx.x;
    const int* raw; const int* lo; const int* boff; int* off; int* csr;
    if (k < NB2) { raw = raw_p; lo = lo_p; boff = boff_p; off = off_p; csr = csr_p; }
    else { k -= NB2; raw = raw_b; lo = lo_b; boff = boff_b; off = off_b; csr = csr_b; }
    const int tid = threadIdx.x;
    cnt[tid] = 0;
    if (tid < NCHUNK) {
        sb[tid] = lo[tid * LOSTRIDE + k];
        se[tid] = lo[tid * LOSTRIDE + k + 1];
    }
    __syncthreads();
    if (tid < NCHUNK) {
        const int base = tid * CHUNK;
        for (int e = sb[tid]; e < se[tid]; ++e)
            atomicAdd(&cnt[raw[base + e] & 255], 1);
    }
    __syncthreads();
    if (tid == 0) {
        int run = 0;
        for (int i = 0; i < 256; ++i) { cur[i] = run; run += cnt[i]; }
    }
    __syncthreads();
    const int bbeg = boff[k];
    const int bsz  = boff[k + 1] - bbeg;
    {
        const int node = (k << 8) + tid;
        if (node < N_NODES) off[node] = bbeg + cur[tid];
    }
    __syncthreads();
    if (bsz <= BCAP) {
        if (tid < NCHUNK) {
            const int base = tid * CHUNK;
            for (int e = sb[tid]; e < se[tid]; ++e) {
                const int id = raw[base + e];
                const int pos = atomicAdd(&cur[id & 255], 1);
                stage[pos] = id >> 8;
            }
        }
        __syncthreads();
        for (int i = tid; i < bsz; i += 256)
            csr[bbeg + i] = stage[i];
    } else {
        if (tid < NCHUNK) {
            const int base = tid * CHUNK;
            for (int e = sb[tid]; e < se[tid]; ++e) {
                const int id = raw[base + e];
                const int pos = atomicAdd(&cur[id & 255], 1);
                csr[bbeg + pos] = id >> 8;
            }
        }
    }
}

// ---------- phase B: both gathers ----------
__global__ __launch_bounds__(256) void phaseB(
    int bstart,
    const u16* __restrict__ fAb, const int* __restrict__ off_b, const int* __restrict__ csr_b,
    float* __restrict__ agg1,
    const u16* __restrict__ fUb, const int* __restrict__ off_p, const int* __restrict__ csr_p,
    float* __restrict__ agg2)
{
    int node = (((blockIdx.x + bstart) * 256 + threadIdx.x) >> 6);
    const u16* featb; const int* off; const int* csr; float* agg;
    if (node < N_NODES) { featb = fAb; off = off_b; csr = csr_b; agg = agg1; }
    else { node -= N_NODES; featb = fUb; off = off_p; csr = csr_p; agg = agg2; }
    const int lane = threadIdx.x & 63;
    const int grp  = lane >> 3;
    const int q    = lane & 7;
    const u32* fb = (const u32*)featb;
    const int beg = off[node], end = off[node + 1];
    float a0=0.f,a1=0.f,a2=0.f,a3=0.f,a4=0.f,a5=0.f,a6=0.f,a7=0.f;
    for (int e = beg + grp; e < end; e += 8) {
        const int s = csr[e];
        const uint4 v = *(const uint4*)&fb[((size_t)s << 5) + (q << 2)];
        a0 += bflo(v.x); a1 += bfhi(v.x);
        a2 += bflo(v.y); a3 += bfhi(v.y);
        a4 += bflo(v.z); a5 += bfhi(v.z);
        a6 += bflo(v.w); a7 += bfhi(v.w);
    }
    #pragma unroll
    for (int m = 8; m <= 32; m <<= 1) {
        a0 += __shfl_xor(a0, m, 64); a1 += __shfl_xor(a1, m, 64);
        a2 += __shfl_xor(a2, m, 64); a3 += __shfl_xor(a3, m, 64);
        a4 += __shfl_xor(a4, m, 64); a5 += __shfl_xor(a5, m, 64);
        a6 += __shfl_xor(a6, m, 64); a7 += __shfl_xor(a7, m, 64);
    }
    if (grp == 0) {
        const float inv = 1.0f / fmaxf((float)(end - beg), 1.0f);
        float4 o0 = make_float4(a0 * inv, a1 * inv, a2 * inv, a3 * inv);
        float4 o1 = make_float4(a4 * inv, a5 * inv, a6 * inv, a7 * inv);
        *(float4*)&agg[(size_t)node * H + 8 * q]     = o0;
        *(float4*)&agg[(size_t)node * H + 8 * q + 4] = o1;
    }
}

// ---------- phase C: both SAGE updates ----------
__global__ __launch_bounds__(256) void phaseC(
    int bstart,
    const float* __restrict__ agg1, const float* __restrict__ xu,
    const u32* __restrict__ pb_h, const u32* __restrict__ pb_l, const float* __restrict__ bl_b,
    const float* __restrict__ agg2, const float* __restrict__ xa,
    const u32* __restrict__ pp_h, const u32* __restrict__ pp_l, const float* __restrict__ bl_p,
    const float* __restrict__ headW, float* __restrict__ z, float* __restrict__ outA)
{
    __shared__ u32 Ah[4096], Al[4096];
    union ShW { u32 w[4096]; float us[64 * 65]; };
    __shared__ ShW shw;
    int blk = blockIdx.x + bstart;
    const bool zhead = (blk < GB);
    const float* A1; const float* A2; const u32* wh_g; const u32* wl_g; const float* bias;
    if (zhead) { A1 = agg1; A2 = xu; wh_g = pb_h; wl_g = pb_l; bias = bl_b; }
    else { blk -= GB; A1 = agg2; A2 = xa; wh_g = pp_h; wl_g = pp_l; bias = bl_p; }
    const int tid  = threadIdx.x;
    const int base = blk * 64;
    const int l  = tid & 63;
    const int wv = tid >> 6;
    const int arow = wv * 16 + (l & 15);
    const int kg = l >> 4;
    f32x4 acc[4] = {};

    for (int i = tid; i < 4096; i += 256) {
        const int row = i >> 6, u = i & 63;
        const int k = 2 * u;
        const int rr = min(base + row, N_NODES - 1);
        const float2 v = (k < 64)
            ? *(const float2*)&A1[(size_t)rr * H + k]
            : *(const float2*)&A2[(size_t)rr * H + (k - 64)];
        u32 h0, l0, h1, l1;
        bfsplit(v.x, h0, l0); bfsplit(v.y, h1, l1);
        const int widx = (row << 6) | (u ^ ((row & 7) << 2));
        Ah[widx] = h0 | (h1 << 16);
        Al[widx] = l0 | (l1 << 16);
    }

    #pragma unroll
    for (int t = 0; t < 2; ++t) {
        for (int i = tid; i < 2048; i += 256) {
            const int row = i >> 5, u = i & 31;
            const int widx = (row << 5) | (u ^ ((row & 7) << 2));
            shw.w[widx]        = wh_g[row * 64 + t * 32 + u];
            shw.w[2048 + widx] = wl_g[row * 64 + t * 32 + u];
        }
        __syncthreads();
        #pragma unroll
        for (int s = 0; s < 2; ++s) {
            const int ka = (arow << 6) + ((t * 32 + s * 16 + kg * 4) ^ ((arow & 7) << 2));
            const bf16x8 ah = *(const bf16x8*)&Ah[ka];
            const bf16x8 al = *(const bf16x8*)&Al[ka];
            #pragma unroll
            for (int c = 0; c < 4; ++c) {
                const int brow = c * 16 + (l & 15);
                const int kb = (brow << 5) + ((s * 16 + kg * 4) ^ ((brow & 7) << 2));
                const bf16x8 bh = *(const bf16x8*)&shw.w[kb];
                const bf16x8 bl = *(const bf16x8*)&shw.w[2048 + kb];
                acc[c] = __builtin_amdgcn_mfma_f32_16x16x32_bf16(ah, bh, acc[c], 0, 0, 0);
                acc[c] = __builtin_amdgcn_mfma_f32_16x16x32_bf16(ah, bl, acc[c], 0, 0, 0);
                acc[c] = __builtin_amdgcn_mfma_f32_16x16x32_bf16(al, bh, acc[c], 0, 0, 0);
            }
        }
        __syncthreads();
    }

    const int r0 = wv * 16 + (l >> 4) * 4;
    if (!zhead) {
        #pragma unroll
        for (int c = 0; c < 4; ++c) {
            const int col = c * 16 + (l & 15);
            const float bv = bias[col];
            #pragma unroll
            for (int i = 0; i < 4; ++i) {
                const int row = base + r0 + i;
                if (row < N_NODES)
                    outA[(size_t)row * H + col] = fmaxf(acc[c][i] + bv, 0.f);
            }
        }
    } else {
        #pragma unroll
        for (int c = 0; c < 4; ++c) {
            const int col = c * 16 + (l & 15);
            const float bv = bias[col];
            #pragma unroll
            for (int i = 0; i < 4; ++i)
                shw.us[(r0 + i) * 65 + col] = fmaxf(acc[c][i] + bv, 0.f);
        }
        __syncthreads();
        if (tid < 128) {
            const int r = tid & 63, o = tid >> 6;
            const int row = base + r;
            if (row < N_NODES) {
                float v = 0.f;
                for (int k = 0; k < 64; ++k)
                    v += shw.us[r * 65 + k] * headW[o * 64 + k];
                z[(size_t)row * 2 + o] = v;
            }
        }
    }
}

// ---------- final head ----------
__global__ __launch_bounds__(256) void final_head(
    const int* __restrict__ off, const int* __restrict__ csr,
    const float* __restrict__ z, const float* __restrict__ a1,
    const float* __restrict__ headW, float* __restrict__ out)
{
    const int node = (blockIdx.x * 256 + threadIdx.x) >> 6;
    const int lane = threadIdx.x & 63;
    const int beg = off[node], end = off[node + 1];
    float z0 = 0.f, z1 = 0.f;
    for (int e = beg + lane; e < end; e += 64) {
        int s = csr[e];
        const float2 zv = *(const float2*)&z[(size_t)s * 2];
        z0 += zv.x; z1 += zv.y;
    }
    const float av = a1[(size_t)node * H + lane];
    float p0 = av * headW[128 + lane];
    float p1 = av * headW[192 + lane];
    #pragma unroll
    for (int m = 1; m <= 32; m <<= 1) {
        z0 += __shfl_xor(z0, m, 64);
        z1 += __shfl_xor(z1, m, 64);
        p0 += __shfl_xor(p0, m, 64);
        p1 += __shfl_xor(p1, m, 64);
    }
    if (lane == 0) {
        const float inv = 1.0f / fmaxf((float)(end - beg), 1.0f);
        float2 o;
        o.x = z0 * inv + p0 + headW[256];
        o.y = z1 * inv + p1 + headW[257];
        *(float2*)&out[(size_t)node * 2] = o;
    }
}

extern "C" void kernel_launch(void* const* d_in, const int* in_sizes, int n_in,
                              void* d_out, int out_size, void* d_ws, size_t ws_size,
                              hipStream_t stream) {
    const float* x_a    = (const float*)d_in[0];
    const float* x_u    = (const float*)d_in[1];
    const int*   ei_p   = (const int*)d_in[2];
    const int*   ei_b   = (const int*)d_in[3];
    const float* w_in_a = (const float*)d_in[4];
    const float* b_in_a = (const float*)d_in[5];
    const float* w_in_u = (const float*)d_in[6];
    const float* b_in_u = (const float*)d_in[7];
    const float* c1p_wl = (const float*)d_in[8];
    const float* c1p_bl = (const float*)d_in[9];
    const float* c1p_wr = (const float*)d_in[10];
    const float* c1b_wl = (const float*)d_in[11];
    const float* c1b_bl = (const float*)d_in[12];
    const float* c1b_wr = (const float*)d_in[13];
    const float* c2p_wl = (const float*)d_in[14];
    const float* c2p_bl = (const float*)d_in[15];
    const float* c2p_wr = (const float*)d_in[16];
    const float* w_out  = (const float*)d_in[20];
    const float* b_out  = (const float*)d_in[21];

    const size_t NF = (size_t)N_NODES * H;
    const size_t PAR_NEED =
        (4 * NF + NF + 2 * N_NODES + 512) * 4 +
        ((size_t)2 * 77056 + 4 * 512 + 2 * OFFPAD + 2 * EDGES) * 4 +
        (size_t)40960 * 4;
    const bool par = ws_size >= PAR_NEED;

    float* bufA  = (float*)d_ws;
    float* bufU  = bufA + NF;
    float* agg1  = bufU + NF;
    float* agg2  = par ? (agg1 + NF) : agg1;
    float* nxt   = par ? (agg2 + NF) : (agg1 + NF);
    u16*   fAb   = (u16*)nxt;
    u16*   fUb   = fAb + NF;
    float* z     = (float*)(fUb + NF);
    float* headW = z + 2 * N_NODES;
    int* lo_p   = (int*)(headW + 512);
    int* lo_b   = lo_p + 77056;
    int* sz_p   = lo_b + 77056;
    int* sz_b   = sz_p + 512;
    int* boff_p = sz_b + 512;
    int* boff_b = boff_p + 512;
    int* off_p  = boff_b + 512;
    int* off_b  = off_p + OFFPAD;
    int* csr_p  = off_b + OFFPAD;
    int* csr_b  = csr_p + EDGES;
    u32* pa_h   = (u32*)(csr_b + EDGES);
    u32* pa_l   = pa_h + 10240;
    u32* pu_h   = pa_l + 10240;
    u32* pu_l   = pu_h + 2048;
    u32* pb_h   = pu_l + 2048;
    u32* pb_l   = pb_h + 4096;
    u32* pp_h   = pb_l + 4096;
    u32* pp_l   = pp_h + 4096;
    int* raw_p  = (int*)agg1;
    int* raw_b  = raw_p + EDGES;

    const dim3 blk(256);

    prep_weights<<<81, blk, 0, stream>>>(
        w_in_a, w_in_u, c1b_wl, c1b_wr, c1p_wl, c1p_wr,
        pa_h, pa_l, pu_h, pu_l, pb_h, pb_l, pp_h, pp_l,
        w_out, c2p_wl, c2p_wr, c2p_bl, b_out, headW, sz_p);

    phaseA<<<GP300 + GSORT + GP64, blk, 0, stream>>>(
        x_a, pa_h, pa_l, b_in_a, bufA, fAb,
        x_u, pu_h, pu_l, b_in_u, bufU, fUb,
        ei_p, ei_b, lo_p, lo_b, sz_p, sz_b, raw_p, raw_b);

    scan_boff<<<2, blk, 0, stream>>>(sz_p, sz_b, boff_p, boff_b, off_p, off_b);
    bucket_sort2<<<2 * NB2, blk, 0, stream>>>(
        raw_p, raw_b, lo_p, lo_b, boff_p, boff_b, off_p, off_b, csr_p, csr_b);

    if (par) {
        phaseB<<<50000, blk, 0, stream>>>(0, fAb, off_b, csr_b, agg1, fUb, off_p, csr_p, agg2);
        phaseC<<<2 * GB, blk, 0, stream>>>(0,
            agg1, bufU, pb_h, pb_l, c1b_bl,
            agg2, bufA, pp_h, pp_l, c1p_bl, headW, z, bufA);
    } else {
        phaseB<<<25000, blk, 0, stream>>>(0, fAb, off_b, csr_b, agg1, fUb, off_p, csr_p, agg2);
        phaseC<<<GB, blk, 0, stream>>>(0,
            agg1, bufU, pb_h, pb_l, c1b_bl,
            agg2, bufA, pp_h, pp_l, c1p_bl, headW, z, bufA);
        phaseB<<<25000, blk, 0, stream>>>(25000, fAb, off_b, csr_b, agg1, fUb, off_p, csr_p, agg2);
        phaseC<<<GB, blk, 0, stream>>>(GB,
            agg1, bufU, pb_h, pb_l, c1b_bl,
            agg2, bufA, pp_h, pp_l, c1p_bl, headW, z, bufA);
    }

    final_head<<<25000, blk, 0, stream>>>(off_p, csr_p, z, bufA, headW, (float*)d_out);

    (void)in_sizes; (void)n_in; (void)out_size;
}